// Round 18
// baseline (167.049 us; speedup 1.0000x reference)
//
#include <hip/hip_runtime.h>
#include <cstdint>
#include <cstddef>

#define D_IN   128
#define D_HID  32
#define D_OUT  32
#define NEG_SLOPE 0.2f
#define EPS_F  1e-16f

#define BKT_SHIFT 9       // 512 nodes per bucket
#define NPB (1 << BKT_SHIFT)
#define KBUKMAX 256       // supports N <= 131072
#define NBLK_BIN 512      // blocks for reserve_scatter
#define BCAP 10240        // per-bucket region capacity (mean 8704, +16 sigma)
#define AGG_BLOCKS 2048   // persistent agg launch

using half4 = __attribute__((ext_vector_type(4))) _Float16;

__device__ __forceinline__ int edge_val(const int* __restrict__ ei, long long idx, int is64) {
    return is64 ? ei[idx * 2] : ei[idx];
}

// Inline int32/int64 detection: values < 2^17, so int64 => every odd int32
// word (high half, LE) of the first 64 pairs is 0. One ballot in wave 0.
__device__ __forceinline__ int detect_is64(const int* __restrict__ ei, long long E,
                                           int t, int* s_is64) {
    if (t < 64) {
        long long n = E < 64 ? E : 64;
        int bad = (t < n && ei[2 * t + 1] != 0) ? 1 : 0;
        unsigned long long mask = __ballot(bad);
        if (t == 0) *s_is64 = (mask == 0ULL) ? 1 : 0;
    }
    __syncthreads();
    return *s_is64;
}

// ---------------------------------------------------------------------------
// FUSED multi-split: per block, (1) LDS histogram of its edge slice,
// (2) ONE global atomicAdd per bucket reserves a contiguous run inside the
// bucket's fixed region, (3) scatter into the run (edge slice re-read hits
// L2). One HBM pass over the edge list instead of two + no scan kernels.
// ---------------------------------------------------------------------------
__global__ __launch_bounds__(256) void reserve_scatter_kernel(
        const int* __restrict__ ei, long long E, long long E2,
        int* __restrict__ gcur, unsigned* __restrict__ bins, int K2, int EPB) {
    __shared__ int hcnt[KBUKMAX];
    __shared__ int cur[KBUKMAX];
    __shared__ int s_is64;
    const int t = threadIdx.x;
    if (t < K2) hcnt[t] = 0;
    const int is64 = detect_is64(ei, E, t, &s_is64);   // has __syncthreads
    const long long lo = (long long)blockIdx.x * EPB;
    const long long hi = min(E2, lo + EPB);
    // phase 1: local histogram (reads dst half of edge list)
    for (long long e = lo + t; e < hi; e += 256) {
        int d = (e < E) ? edge_val(ei, E + e, is64) : (int)(e - E);
        atomicAdd(&hcnt[d >> BKT_SHIFT], 1);
    }
    __syncthreads();
    // phase 2: reserve a run per bucket
    if (t < K2) {
        int n = hcnt[t];
        cur[t] = (n > 0) ? atomicAdd(&gcur[t], n) : 0;
    }
    __syncthreads();
    // phase 3: scatter (edge slice re-read, L2-hot)
    for (long long e = lo + t; e < hi; e += 256) {
        int s, d;
        if (e < E) { s = edge_val(ei, e, is64); d = edge_val(ei, E + e, is64); }
        else       { s = d = (int)(e - E); }
        int b = d >> BKT_SHIFT;
        int pos = atomicAdd(&cur[b], 1);
        if (pos < BCAP)
            bins[(long long)b * BCAP + pos] = (unsigned)s | ((unsigned)(d & (NPB - 1)) << 17);
    }
}

// ---------------------------------------------------------------------------
// Fused CSR build, one block per 512-node bucket. Bucket's global CSR base
// is derived in-block by scanning the 196 bucket counts (gcur).
// ---------------------------------------------------------------------------
__global__ __launch_bounds__(512) void csr_b_kernel(
        const unsigned* __restrict__ bins, const int* __restrict__ gcur,
        int* __restrict__ rowptr, float* __restrict__ dis, int* __restrict__ csr_src,
        int N, int K2, long long E2) {
    __shared__ int lcur[NPB];
    __shared__ int wsum[8];
    __shared__ int bbase_s, bcnt_s;
    const int b = blockIdx.x, t = threadIdx.x;     // 512 threads
    const int nbase = b << BKT_SHIFT;
    const int nn = min(NPB, N - nbase);
    lcur[t] = 0;
    const int lane = t & 63, wid = t >> 6;
    // ---- scan bucket counts -> this bucket's global CSR base ----
    int cntb = (t < K2) ? min(gcur[t], BCAP) : 0;
    {
        int incl = cntb;
        #pragma unroll
        for (int d = 1; d < 64; d <<= 1) {
            int u = __shfl_up(incl, d);
            if (lane >= d) incl += u;
        }
        if (lane == 63) wsum[wid] = incl;
        __syncthreads();
        int woff = 0;
        for (int w = 0; w < wid; ++w) woff += wsum[w];
        int excl = woff + incl - cntb;
        if (t == b) { bbase_s = excl; bcnt_s = cntb; }
        __syncthreads();
    }
    const int base = bbase_s;                      // global CSR offset of bucket
    const int cnt  = bcnt_s;
    const unsigned* bp = bins + (long long)b * BCAP;
    // ---- per-node degree count ----
    for (int i = t; i < cnt; i += 512)
        atomicAdd(&lcur[bp[i] >> 17], 1);
    __syncthreads();
    // ---- 512-wide node exclusive scan ----
    int v = lcur[t];
    int incl = v;
    #pragma unroll
    for (int d = 1; d < 64; d <<= 1) {
        int u = __shfl_up(incl, d);
        if (lane >= d) incl += u;
    }
    if (lane == 63) wsum[wid] = incl;
    __syncthreads();
    int woff = 0;
    for (int w = 0; w < wid; ++w) woff += wsum[w];
    int excl = woff + incl - v;
    if (t < nn) {
        rowptr[nbase + t] = base + excl;
        dis[nbase + t] = rsqrtf((float)v);         // deg >= 1 (self-loop)
    }
    __syncthreads();
    lcur[t] = base + excl;
    __syncthreads();
    // ---- scatter into this bucket's contiguous CSR window ----
    for (int i = t; i < cnt; i += 512) {
        unsigned u = bp[i];
        int pos = atomicAdd(&lcur[u >> 17], 1);
        csr_src[pos] = (int)(u & 0x1FFFFu);
    }
    if (b == 0 && t == 0) rowptr[N] = (int)E2;
}

// ---------------------------------------------------------------------------
// gemm1 v4: thread-per-row, 32 accumulators. Max MLP on x loads; W1 LDS
// broadcast (conflict-free). hws_h = fp16(dis*(x@W1)). Zeroes sentinel row N.
// ---------------------------------------------------------------------------
__global__ __launch_bounds__(256) void gemm1_kernel(
        const float* __restrict__ x, const float* __restrict__ W1,
        const float* __restrict__ dis, _Float16* __restrict__ hws_h, int N) {
    __shared__ float sW[D_IN * D_HID];             // 16 KB, layout [k][c]
    const int t = threadIdx.x;
    for (int i = t; i < D_IN * D_HID; i += 256) sW[i] = W1[i];
    __syncthreads();
    if (blockIdx.x == 0 && t < 8) {                // zero sentinel row N
        half4 z;
        z.x = (_Float16)0.f; z.y = (_Float16)0.f;
        z.z = (_Float16)0.f; z.w = (_Float16)0.f;
        ((half4*)hws_h)[(long long)N * 8 + t] = z;
    }
    long long row = (long long)blockIdx.x * 256 + t;
    const bool valid = row < N;
    long long r = valid ? row : (long long)(N - 1);
    const float4* x4 = (const float4*)x;
    float acc[D_HID];
    #pragma unroll
    for (int c = 0; c < D_HID; ++c) acc[c] = 0.f;
    for (int q = 0; q < 32; ++q) {
        float4 xv = x4[r * 32 + q];
        #pragma unroll
        for (int kk = 0; kk < 4; ++kk) {
            float xs = (&xv.x)[kk];
            const float* wrow = &sW[(q * 4 + kk) * D_HID];
            #pragma unroll
            for (int c4 = 0; c4 < 8; ++c4) {
                float4 wv = *(const float4*)&wrow[c4 * 4];
                acc[c4 * 4 + 0] = fmaf(xs, wv.x, acc[c4 * 4 + 0]);
                acc[c4 * 4 + 1] = fmaf(xs, wv.y, acc[c4 * 4 + 1]);
                acc[c4 * 4 + 2] = fmaf(xs, wv.z, acc[c4 * 4 + 2]);
                acc[c4 * 4 + 3] = fmaf(xs, wv.w, acc[c4 * 4 + 3]);
            }
        }
    }
    if (valid) {
        float dd = dis[r];
        half4* hh4 = (half4*)hws_h;
        #pragma unroll
        for (int c4 = 0; c4 < 8; ++c4) {
            half4 o;
            o.x = (_Float16)(acc[c4 * 4 + 0] * dd);
            o.y = (_Float16)(acc[c4 * 4 + 1] * dd);
            o.z = (_Float16)(acc[c4 * 4 + 2] * dd);
            o.w = (_Float16)(acc[c4 * 4 + 3] * dd);
            hh4[r * 8 + c4] = o;
        }
    }
}

// ---------------------------------------------------------------------------
// FUSED GCN aggregate + ReLU + gemm2 + attention logits (R16 form: 4-deep
// gather, sentinel row for tails, W2 column in regs, h1 never in memory).
// ---------------------------------------------------------------------------
__global__ __launch_bounds__(256) void gcn_fused_kernel(
        const int* __restrict__ rowptr, const int* __restrict__ csr_src,
        const _Float16* __restrict__ hws_h, const float* __restrict__ dis,
        const float* __restrict__ b1, const float* __restrict__ W2,
        const float* __restrict__ att_s, const float* __restrict__ att_d,
        _Float16* __restrict__ g_h, float* __restrict__ a_s, float* __restrict__ a_d,
        int N) {
    __shared__ float sW2[D_HID * D_OUT];           // 4 KB, [k][c]
    __shared__ float sas[D_OUT], sad[D_OUT];
    const int t = threadIdx.x;
    for (int i = t; i < D_HID * D_OUT; i += 256) sW2[i] = W2[i];
    if (t < D_OUT) { sas[t] = att_s[t]; sad[t] = att_d[t]; }
    __syncthreads();
    const int lane = t & 63;
    const int half = lane >> 5, l32 = lane & 31;
    const int u = l32 & 7, grp = l32 >> 3;         // 4 groups x 8 lanes per node
    const int wib = t >> 6;                        // 4 waves / block
    const half4* hh4 = (const half4*)hws_h;
    const float4 b14 = ((const float4*)b1)[u];
    float w2c[D_HID];
    #pragma unroll
    for (int k = 0; k < D_HID; ++k) w2c[k] = sW2[k * D_OUT + l32];
    const float sasl = sas[l32], sadl = sad[l32];
    const int srcBase = half * 32;
    const int npair = (N + 1) >> 1;
    for (int p = blockIdx.x * 4 + wib; p < npair; p += gridDim.x * 4) {
        const int i = p * 2 + half;
        const bool act = i < N;
        int b = 0, e = 0;
        if (act) { b = rowptr[i]; e = rowptr[i + 1]; }
        float ax = 0.f, ay = 0.f, az = 0.f, aw = 0.f;
        for (int j = b + grp; j < e; j += 16) {    // 4-deep: slots j, j+4, j+8, j+12
            int j1 = j + 4, j2 = j + 8, j3 = j + 12;
            bool v1 = j1 < e, v2 = j2 < e, v3 = j3 < e;
            int s0 = csr_src[j];
            int s1 = v1 ? csr_src[v1 ? j1 : j] : N;   // row N is zeroed sentinel
            int s2 = v2 ? csr_src[v2 ? j2 : j] : N;
            int s3 = v3 ? csr_src[v3 ? j3 : j] : N;
            half4 h0 = hh4[s0 * 8 + u];
            half4 h1 = hh4[s1 * 8 + u];
            half4 h2 = hh4[s2 * 8 + u];
            half4 h3 = hh4[s3 * 8 + u];
            ax += (float)h0.x + (float)h1.x + (float)h2.x + (float)h3.x;
            ay += (float)h0.y + (float)h1.y + (float)h2.y + (float)h3.y;
            az += (float)h0.z + (float)h1.z + (float)h2.z + (float)h3.z;
            aw += (float)h0.w + (float)h1.w + (float)h2.w + (float)h3.w;
        }
        #pragma unroll
        for (int d = 8; d <= 16; d <<= 1) {        // reduce over 4 groups
            ax += __shfl_xor(ax, d); ay += __shfl_xor(ay, d);
            az += __shfl_xor(az, d); aw += __shfl_xor(aw, d);
        }
        float dd = act ? dis[i] : 0.f;
        float4 o;
        o.x = fmaf(dd, ax, b14.x); o.y = fmaf(dd, ay, b14.y);
        o.z = fmaf(dd, az, b14.z); o.w = fmaf(dd, aw, b14.w);
        o.x = o.x > 0.f ? o.x : 0.f; o.y = o.y > 0.f ? o.y : 0.f;
        o.z = o.z > 0.f ? o.z : 0.f; o.w = o.w > 0.f ? o.w : 0.f;
        // g[c] for c = l32 via shuffle-broadcast of the 8 chunks; W2 col in regs
        float gv = 0.f;
        #pragma unroll
        for (int up = 0; up < 8; ++up) {
            int sl = srcBase + up;
            float hx = __shfl(o.x, sl);
            float hy = __shfl(o.y, sl);
            float hz = __shfl(o.z, sl);
            float hw = __shfl(o.w, sl);
            gv = fmaf(hx, w2c[up * 4 + 0], gv);
            gv = fmaf(hy, w2c[up * 4 + 1], gv);
            gv = fmaf(hz, w2c[up * 4 + 2], gv);
            gv = fmaf(hw, w2c[up * 4 + 3], gv);
        }
        if (act) g_h[(long long)i * D_OUT + l32] = (_Float16)gv;
        float ps = gv * sasl;
        float pd = gv * sadl;
        #pragma unroll
        for (int d = 1; d <= 16; d <<= 1) {
            ps += __shfl_xor(ps, d);
            pd += __shfl_xor(pd, d);
        }
        if (act && l32 == 0) { a_s[i] = ps; a_d[i] = pd; }
    }
}

// ---------------------------------------------------------------------------
// e_pre v3: per-edge logits AND per-node max (exact reference segment-max).
// ---------------------------------------------------------------------------
__global__ __launch_bounds__(256) void e_pre_kernel(
        const int* __restrict__ rowptr, const int* __restrict__ csr_src,
        const float* __restrict__ a_s, const float* __restrict__ a_d,
        float* __restrict__ epre, float* __restrict__ mrow, int N) {
    int i = blockIdx.x * blockDim.x + threadIdx.x;
    if (i >= N) return;
    const int b = rowptr[i], e = rowptr[i + 1];
    const float adi = a_d[i];
    float m = -1e30f;
    for (int j = b; j < e; ++j) {
        float ev = a_s[csr_src[j]] + adi;
        ev = ev > 0.f ? ev : NEG_SLOPE * ev;
        epre[j] = ev;
        m = fmaxf(m, ev);
    }
    mrow[i] = m;
}

// ---------------------------------------------------------------------------
// GAT aggregate: single-exp weighted gather-sum (max precomputed). 2 nodes
// per wave, 4-deep gather unroll (R16 form).
// ---------------------------------------------------------------------------
__global__ void gat_agg_kernel(const int* __restrict__ rowptr, const int* __restrict__ csr_src,
                               const _Float16* __restrict__ g_h, const float* __restrict__ epre,
                               const float* __restrict__ mrow, const float* __restrict__ b2,
                               float* __restrict__ out, int N) {
    const int lane = threadIdx.x & 63;
    const int half = lane >> 5, l32 = lane & 31;
    const int u = l32 & 7, grp = l32 >> 3;         // 4 groups x 8 lanes per node
    const int wib = threadIdx.x >> 6;
    const half4* gh4 = (const half4*)g_h;
    float4* out4 = (float4*)out;
    const float4 b24 = ((const float4*)b2)[u];
    const int npair = (N + 1) >> 1;
    for (int p = blockIdx.x * 4 + wib; p < npair; p += gridDim.x * 4) {
        const int i = p * 2 + half;
        const bool act = i < N;
        int b = 0, e = 0;
        float mi = 0.f;
        if (act) { b = rowptr[i]; e = rowptr[i + 1]; mi = mrow[i]; }
        float ssum = 0.f;
        float ax = 0.f, ay = 0.f, az = 0.f, aw = 0.f;
        for (int j = b + grp; j < e; j += 16) {    // 4-deep: slots j, j+4, j+8, j+12
            int j1 = j + 4, j2 = j + 8, j3 = j + 12;
            bool v1 = j1 < e, v2 = j2 < e, v3 = j3 < e;
            int s0 = csr_src[j];
            int s1 = csr_src[v1 ? j1 : j];
            int s2 = csr_src[v2 ? j2 : j];
            int s3 = csr_src[v3 ? j3 : j];
            float e0 = epre[j];
            float e1 = epre[v1 ? j1 : j];
            float e2 = epre[v2 ? j2 : j];
            float e3 = epre[v3 ? j3 : j];
            half4 g0 = gh4[s0 * 8 + u];
            half4 g1 = gh4[s1 * 8 + u];
            half4 g2 = gh4[s2 * 8 + u];
            half4 g3 = gh4[s3 * 8 + u];
            float w0 = __expf(e0 - mi);
            float w1 = v1 ? __expf(e1 - mi) : 0.f;
            float w2 = v2 ? __expf(e2 - mi) : 0.f;
            float w3 = v3 ? __expf(e3 - mi) : 0.f;
            ssum += w0 + w1 + w2 + w3;
            ax = fmaf(w0, (float)g0.x, fmaf(w1, (float)g1.x, fmaf(w2, (float)g2.x, fmaf(w3, (float)g3.x, ax))));
            ay = fmaf(w0, (float)g0.y, fmaf(w1, (float)g1.y, fmaf(w2, (float)g2.y, fmaf(w3, (float)g3.y, ay))));
            az = fmaf(w0, (float)g0.z, fmaf(w1, (float)g1.z, fmaf(w2, (float)g2.z, fmaf(w3, (float)g3.z, az))));
            aw = fmaf(w0, (float)g0.w, fmaf(w1, (float)g1.w, fmaf(w2, (float)g2.w, fmaf(w3, (float)g3.w, aw))));
        }
        #pragma unroll
        for (int d = 8; d <= 16; d <<= 1) {        // reduce over 4 groups
            ssum += __shfl_xor(ssum, d);
            ax += __shfl_xor(ax, d); ay += __shfl_xor(ay, d);
            az += __shfl_xor(az, d); aw += __shfl_xor(aw, d);
        }
        if (act && grp == 0) {
            float inv = 1.f / (ssum + EPS_F);
            float4 o;
            o.x = fmaf(ax, inv, b24.x); o.y = fmaf(ay, inv, b24.y);
            o.z = fmaf(az, inv, b24.z); o.w = fmaf(aw, inv, b24.w);
            out4[(long long)i * 8 + u] = o;
        }
    }
}

extern "C" void kernel_launch(void* const* d_in, const int* in_sizes, int n_in,
                              void* d_out, int out_size, void* d_ws, size_t ws_size,
                              hipStream_t stream) {
    const float* x       = (const float*)d_in[0];
    const int*   ei      = (const int*)d_in[1];   // int32 or int64, detected on device
    const float* W1      = (const float*)d_in[2];
    const float* b1      = (const float*)d_in[3];
    const float* W2      = (const float*)d_in[4];
    const float* att_src = (const float*)d_in[5];
    const float* att_dst = (const float*)d_in[6];
    const float* b2      = (const float*)d_in[7];
    float* out = (float*)d_out;

    const long long N  = in_sizes[0] / D_IN;
    const long long E  = in_sizes[1] / 2;
    const long long E2 = E + N;
    const int K2  = (int)((N + NPB - 1) >> BKT_SHIFT);              // 196 for N=100K
    const int EPB = (int)((E2 + NBLK_BIN - 1) / NBLK_BIN);

    // workspace layout (256B aligned slices)
    char* ws = (char*)d_ws;
    size_t off0 = 0;
    auto alloc = [&](size_t bytes) -> void* {
        off0 = (off0 + 255) & ~(size_t)255;
        void* p = ws + off0;
        off0 += bytes;
        return p;
    };
    int*   gcur     = (int*)  alloc((size_t)KBUKMAX * 4);
    unsigned* bins  = (unsigned*)alloc((size_t)K2 * BCAP * 4);
    int*   rowptr   = (int*)  alloc((size_t)(N + 1) * 4);
    int*   csr_src  = (int*)  alloc((size_t)E2 * 4);
    float* dis      = (float*)alloc((size_t)N * 4);
    _Float16* hws_h = (_Float16*)alloc((size_t)(N + 1) * D_HID * 2);  // +1 sentinel row
    _Float16* g_h   = (_Float16*)alloc((size_t)(N + 1) * D_OUT * 2);
    float* as       = (float*)alloc((size_t)N * 4);
    float* ad       = (float*)alloc((size_t)N * 4);
    float* epre     = (float*)alloc((size_t)E2 * 4);
    float* mrow     = (float*)alloc((size_t)N * 4);
    (void)ws_size; (void)n_in; (void)out_size;

    hipMemsetAsync(gcur, 0, (size_t)K2 * 4, stream);
    reserve_scatter_kernel<<<NBLK_BIN, 256, 0, stream>>>(ei, E, E2, gcur, bins, K2, EPB);
    csr_b_kernel<<<K2, 512, 0, stream>>>(bins, gcur, rowptr, dis, csr_src, (int)N, K2, E2);
    gemm1_kernel<<<(int)((N + 255) / 256), 256, 0, stream>>>(x, W1, dis, hws_h, (int)N);
    gcn_fused_kernel<<<AGG_BLOCKS, 256, 0, stream>>>(rowptr, csr_src, hws_h, dis, b1, W2,
                                                     att_src, att_dst, g_h, as, ad, (int)N);
    e_pre_kernel<<<(int)((N + 255) / 256), 256, 0, stream>>>(rowptr, csr_src, as, ad, epre, mrow, (int)N);
    gat_agg_kernel<<<AGG_BLOCKS, 256, 0, stream>>>(rowptr, csr_src, g_h, epre, mrow, b2, out, (int)N);
}

// Round 19
// 154.935 us; speedup vs baseline: 1.0782x; 1.0782x over previous
//
#include <hip/hip_runtime.h>
#include <cstdint>
#include <cstddef>

#define D_IN   128
#define D_HID  32
#define D_OUT  32
#define NEG_SLOPE 0.2f
#define EPS_F  1e-16f

#define BKT_SHIFT 9       // 512 nodes per bucket
#define NPB (1 << BKT_SHIFT)
#define KBUKMAX 256       // supports N <= 131072
#define NBLK_BIN 512      // blocks for hist/scatter (runs ~17 entries = 68B, line-dense)
#define AGG_BLOCKS 2048   // persistent agg launch

using half4 = __attribute__((ext_vector_type(4))) _Float16;

__device__ __forceinline__ int edge_val(const int* __restrict__ ei, long long idx, int is64) {
    return is64 ? ei[idx * 2] : ei[idx];
}

// Inline int32/int64 detection: values < 2^17, so int64 => every odd int32
// word (high half, LE) of the first 64 pairs is 0. One ballot in wave 0.
__device__ __forceinline__ int detect_is64(const int* __restrict__ ei, long long E,
                                           int t, int* s_is64) {
    if (t < 64) {
        long long n = E < 64 ? E : 64;
        int bad = (t < n && ei[2 * t + 1] != 0) ? 1 : 0;
        unsigned long long mask = __ballot(bad);
        if (t == 0) *s_is64 = (mask == 0ULL) ? 1 : 0;
    }
    __syncthreads();
    return *s_is64;
}

// ---------------------------------------------------------------------------
// Multi-split pass 1: per-block bucket histogram (LDS), dense write-out.
// ---------------------------------------------------------------------------
__global__ __launch_bounds__(256) void hist_kernel(
        const int* __restrict__ ei, long long E, long long E2,
        int* __restrict__ hist, int K2, int EPB) {
    __shared__ int hcnt[KBUKMAX];
    __shared__ int s_is64;
    const int t = threadIdx.x;
    if (t < K2) hcnt[t] = 0;
    const int is64 = detect_is64(ei, E, t, &s_is64);   // has __syncthreads
    const long long lo = (long long)blockIdx.x * EPB;
    const long long hi = min(E2, lo + EPB);
    for (long long e = lo + t; e < hi; e += 256) {
        int d = (e < E) ? edge_val(ei, E + e, is64) : (int)(e - E);
        atomicAdd(&hcnt[d >> BKT_SHIFT], 1);
    }
    __syncthreads();
    if (t < K2) hist[t * gridDim.x + blockIdx.x] = hcnt[t];
}

// ---------------- hierarchical exclusive scan, phases A+B only ------------
__global__ void scan_ga_kernel(int* __restrict__ a, int* __restrict__ bsum, int L) {
    __shared__ int wsum[4];
    const int t = threadIdx.x;
    const int i0 = blockIdx.x * 1024 + t * 4;
    int v[4]; int s = 0;
    #pragma unroll
    for (int k = 0; k < 4; ++k) {
        v[k] = (i0 + k < L) ? a[i0 + k] : 0;
        s += v[k];
    }
    const int lane = t & 63, wid = t >> 6;
    int incl = s;
    #pragma unroll
    for (int d = 1; d < 64; d <<= 1) {
        int u = __shfl_up(incl, d);
        if (lane >= d) incl += u;
    }
    if (lane == 63) wsum[wid] = incl;
    __syncthreads();
    int woff = 0;
    for (int w = 0; w < wid; ++w) woff += wsum[w];
    int excl = woff + incl - s;
    #pragma unroll
    for (int k = 0; k < 4; ++k) {
        if (i0 + k < L) a[i0 + k] = excl;
        excl += v[k];
    }
    if (t == 255) bsum[blockIdx.x] = woff + incl;
}

__global__ __launch_bounds__(1024) void scan_flat_kernel(int* __restrict__ a, int L) {
    __shared__ int wsum[16];
    __shared__ int carry_s;
    const int t = threadIdx.x;
    const int lane = t & 63, wid = t >> 6;
    if (t == 0) carry_s = 0;
    __syncthreads();
    for (int start = 0; start < L; start += 1024) {
        int idx = start + t;
        int v = (idx < L) ? a[idx] : 0;
        int incl = v;
        #pragma unroll
        for (int d = 1; d < 64; d <<= 1) {
            int u = __shfl_up(incl, d);
            if (lane >= d) incl += u;
        }
        if (lane == 63) wsum[wid] = incl;
        __syncthreads();
        int woff = 0;
        for (int w = 0; w < wid; ++w) woff += wsum[w];
        int carry = carry_s;
        __syncthreads();
        if (idx < L) a[idx] = carry + woff + incl - v;
        if (t == 1023) carry_s = carry + woff + incl;
        __syncthreads();
    }
}

// ---------------------------------------------------------------------------
// Multi-split pass 2: scatter packed (src | dlow<<17) into bins. Offsets =
// hist[idx] + bsum[idx>>10] (phase-C fold).
// ---------------------------------------------------------------------------
__global__ __launch_bounds__(256) void scatter_kernel(
        const int* __restrict__ ei, long long E, long long E2,
        const int* __restrict__ off, const int* __restrict__ bsum,
        unsigned* __restrict__ bins, int K2, int EPB) {
    __shared__ int cur[KBUKMAX];
    __shared__ int s_is64;
    const int t = threadIdx.x;
    if (t < K2) {
        int idx = t * gridDim.x + blockIdx.x;
        cur[t] = off[idx] + bsum[idx >> 10];
    }
    const int is64 = detect_is64(ei, E, t, &s_is64);   // has __syncthreads
    const long long lo = (long long)blockIdx.x * EPB;
    const long long hi = min(E2, lo + EPB);
    for (long long e = lo + t; e < hi; e += 256) {
        int s, d;
        if (e < E) { s = edge_val(ei, e, is64); d = edge_val(ei, E + e, is64); }
        else       { s = d = (int)(e - E); }
        int b = d >> BKT_SHIFT;
        int pos = atomicAdd(&cur[b], 1);
        bins[pos] = (unsigned)s | ((unsigned)(d & (NPB - 1)) << 17);
    }
}

// ---------------------------------------------------------------------------
// Fused CSR build, one block per 512-node bucket.
// ---------------------------------------------------------------------------
__global__ __launch_bounds__(512) void csr_b_kernel(
        const unsigned* __restrict__ bins, const int* __restrict__ off,
        const int* __restrict__ bsum,
        int* __restrict__ rowptr, float* __restrict__ dis, int* __restrict__ csr_src,
        int N, int K2, long long E2) {
    __shared__ int lcur[NPB];
    __shared__ int wsum[8];
    const int b = blockIdx.x, t = threadIdx.x;     // 512 threads
    const int nbase = b << BKT_SHIFT;
    const int nn = min(NPB, N - nbase);
    lcur[t] = 0;
    __syncthreads();
    int bidx = b * NBLK_BIN;
    const int base = off[bidx] + bsum[bidx >> 10];
    int end;
    if (b == K2 - 1) end = (int)E2;
    else {
        int eidx = (b + 1) * NBLK_BIN;
        end = off[eidx] + bsum[eidx >> 10];
    }
    for (int i = base + t; i < end; i += 512)
        atomicAdd(&lcur[bins[i] >> 17], 1);
    __syncthreads();
    const int lane = t & 63, wid = t >> 6;
    int v = lcur[t];
    int incl = v;
    #pragma unroll
    for (int d = 1; d < 64; d <<= 1) {
        int u = __shfl_up(incl, d);
        if (lane >= d) incl += u;
    }
    if (lane == 63) wsum[wid] = incl;
    __syncthreads();
    int woff = 0;
    for (int w = 0; w < wid; ++w) woff += wsum[w];
    int excl = woff + incl - v;
    if (t < nn) {
        rowptr[nbase + t] = base + excl;
        dis[nbase + t] = rsqrtf((float)v);         // deg >= 1 (self-loop)
    }
    __syncthreads();
    lcur[t] = base + excl;
    __syncthreads();
    for (int i = base + t; i < end; i += 512) {
        unsigned u = bins[i];
        int pos = atomicAdd(&lcur[u >> 17], 1);
        csr_src[pos] = (int)(u & 0x1FFFFu);
    }
    if (b == 0 && t == 0) rowptr[N] = (int)E2;
}

// ---------------------------------------------------------------------------
// gemm1 v4: thread-per-row, 32 accumulators. Max MLP on x loads; W1 LDS
// broadcast (conflict-free). hws_h = fp16(dis*(x@W1)). Zeroes sentinel row N.
// ---------------------------------------------------------------------------
__global__ __launch_bounds__(256) void gemm1_kernel(
        const float* __restrict__ x, const float* __restrict__ W1,
        const float* __restrict__ dis, _Float16* __restrict__ hws_h, int N) {
    __shared__ float sW[D_IN * D_HID];             // 16 KB, layout [k][c]
    const int t = threadIdx.x;
    for (int i = t; i < D_IN * D_HID; i += 256) sW[i] = W1[i];
    __syncthreads();
    if (blockIdx.x == 0 && t < 8) {                // zero sentinel row N
        half4 z;
        z.x = (_Float16)0.f; z.y = (_Float16)0.f;
        z.z = (_Float16)0.f; z.w = (_Float16)0.f;
        ((half4*)hws_h)[(long long)N * 8 + t] = z;
    }
    long long row = (long long)blockIdx.x * 256 + t;
    const bool valid = row < N;
    long long r = valid ? row : (long long)(N - 1);
    const float4* x4 = (const float4*)x;
    float acc[D_HID];
    #pragma unroll
    for (int c = 0; c < D_HID; ++c) acc[c] = 0.f;
    for (int q = 0; q < 32; ++q) {
        float4 xv = x4[r * 32 + q];
        #pragma unroll
        for (int kk = 0; kk < 4; ++kk) {
            float xs = (&xv.x)[kk];
            const float* wrow = &sW[(q * 4 + kk) * D_HID];
            #pragma unroll
            for (int c4 = 0; c4 < 8; ++c4) {
                float4 wv = *(const float4*)&wrow[c4 * 4];
                acc[c4 * 4 + 0] = fmaf(xs, wv.x, acc[c4 * 4 + 0]);
                acc[c4 * 4 + 1] = fmaf(xs, wv.y, acc[c4 * 4 + 1]);
                acc[c4 * 4 + 2] = fmaf(xs, wv.z, acc[c4 * 4 + 2]);
                acc[c4 * 4 + 3] = fmaf(xs, wv.w, acc[c4 * 4 + 3]);
            }
        }
    }
    if (valid) {
        float dd = dis[r];
        half4* hh4 = (half4*)hws_h;
        #pragma unroll
        for (int c4 = 0; c4 < 8; ++c4) {
            half4 o;
            o.x = (_Float16)(acc[c4 * 4 + 0] * dd);
            o.y = (_Float16)(acc[c4 * 4 + 1] * dd);
            o.z = (_Float16)(acc[c4 * 4 + 2] * dd);
            o.w = (_Float16)(acc[c4 * 4 + 3] * dd);
            hh4[r * 8 + c4] = o;
        }
    }
}

// ---------------------------------------------------------------------------
// FUSED GCN aggregate + ReLU + gemm2 + attention logits (R16 form) with
// next-pair rowptr prefetch: the int2 rowptr load for iteration p+1 is
// issued before processing iteration p, hiding its latency under gathers.
// ---------------------------------------------------------------------------
__global__ __launch_bounds__(256) void gcn_fused_kernel(
        const int* __restrict__ rowptr, const int* __restrict__ csr_src,
        const _Float16* __restrict__ hws_h, const float* __restrict__ dis,
        const float* __restrict__ b1, const float* __restrict__ W2,
        const float* __restrict__ att_s, const float* __restrict__ att_d,
        _Float16* __restrict__ g_h, float* __restrict__ a_s, float* __restrict__ a_d,
        int N) {
    __shared__ float sW2[D_HID * D_OUT];           // 4 KB, [k][c]
    __shared__ float sas[D_OUT], sad[D_OUT];
    const int t = threadIdx.x;
    for (int i = t; i < D_HID * D_OUT; i += 256) sW2[i] = W2[i];
    if (t < D_OUT) { sas[t] = att_s[t]; sad[t] = att_d[t]; }
    __syncthreads();
    const int lane = t & 63;
    const int half = lane >> 5, l32 = lane & 31;
    const int u = l32 & 7, grp = l32 >> 3;         // 4 groups x 8 lanes per node
    const int wib = t >> 6;                        // 4 waves / block
    const half4* hh4 = (const half4*)hws_h;
    const float4 b14 = ((const float4*)b1)[u];
    float w2c[D_HID];
    #pragma unroll
    for (int k = 0; k < D_HID; ++k) w2c[k] = sW2[k * D_OUT + l32];
    const float sasl = sas[l32], sadl = sad[l32];
    const int srcBase = half * 32;
    const int npair = (N + 1) >> 1;
    const int pstride = gridDim.x * 4;
    int p = blockIdx.x * 4 + wib;
    // prefetch first pair's rowptr range (int2: one 8B load)
    int2 be = make_int2(0, 0);
    if (p < npair) {
        int i0 = p * 2 + half;
        if (i0 < N) be = *(const int2*)&rowptr[i0];
    }
    for (; p < npair; p += pstride) {
        const int i = p * 2 + half;
        const bool act = i < N;
        const int b = be.x, e = be.y;
        // issue next iteration's rowptr load NOW (overlaps with gathers)
        int pn = p + pstride;
        if (pn < npair) {
            int i1 = pn * 2 + half;
            if (i1 < N) be = *(const int2*)&rowptr[i1];
        }
        float ax = 0.f, ay = 0.f, az = 0.f, aw = 0.f;
        for (int j = b + grp; j < e; j += 16) {    // 4-deep: slots j, j+4, j+8, j+12
            int j1 = j + 4, j2 = j + 8, j3 = j + 12;
            bool v1 = j1 < e, v2 = j2 < e, v3 = j3 < e;
            int s0 = csr_src[j];
            int s1 = v1 ? csr_src[v1 ? j1 : j] : N;   // row N is zeroed sentinel
            int s2 = v2 ? csr_src[v2 ? j2 : j] : N;
            int s3 = v3 ? csr_src[v3 ? j3 : j] : N;
            half4 h0 = hh4[s0 * 8 + u];
            half4 h1 = hh4[s1 * 8 + u];
            half4 h2 = hh4[s2 * 8 + u];
            half4 h3 = hh4[s3 * 8 + u];
            ax += (float)h0.x + (float)h1.x + (float)h2.x + (float)h3.x;
            ay += (float)h0.y + (float)h1.y + (float)h2.y + (float)h3.y;
            az += (float)h0.z + (float)h1.z + (float)h2.z + (float)h3.z;
            aw += (float)h0.w + (float)h1.w + (float)h2.w + (float)h3.w;
        }
        #pragma unroll
        for (int d = 8; d <= 16; d <<= 1) {        // reduce over 4 groups
            ax += __shfl_xor(ax, d); ay += __shfl_xor(ay, d);
            az += __shfl_xor(az, d); aw += __shfl_xor(aw, d);
        }
        float dd = act ? dis[i] : 0.f;
        float4 o;
        o.x = fmaf(dd, ax, b14.x); o.y = fmaf(dd, ay, b14.y);
        o.z = fmaf(dd, az, b14.z); o.w = fmaf(dd, aw, b14.w);
        o.x = o.x > 0.f ? o.x : 0.f; o.y = o.y > 0.f ? o.y : 0.f;
        o.z = o.z > 0.f ? o.z : 0.f; o.w = o.w > 0.f ? o.w : 0.f;
        // g[c] for c = l32 via shuffle-broadcast of the 8 chunks; W2 col in regs
        float gv = 0.f;
        #pragma unroll
        for (int up = 0; up < 8; ++up) {
            int sl = srcBase + up;
            float hx = __shfl(o.x, sl);
            float hy = __shfl(o.y, sl);
            float hz = __shfl(o.z, sl);
            float hw = __shfl(o.w, sl);
            gv = fmaf(hx, w2c[up * 4 + 0], gv);
            gv = fmaf(hy, w2c[up * 4 + 1], gv);
            gv = fmaf(hz, w2c[up * 4 + 2], gv);
            gv = fmaf(hw, w2c[up * 4 + 3], gv);
        }
        if (act) g_h[(long long)i * D_OUT + l32] = (_Float16)gv;
        float ps = gv * sasl;
        float pd = gv * sadl;
        #pragma unroll
        for (int d = 1; d <= 16; d <<= 1) {
            ps += __shfl_xor(ps, d);
            pd += __shfl_xor(pd, d);
        }
        if (act && l32 == 0) { a_s[i] = ps; a_d[i] = pd; }
    }
}

// ---------------------------------------------------------------------------
// e_pre v3: per-edge logits AND per-node max; 2-edge ILP in the loop.
// ---------------------------------------------------------------------------
__global__ __launch_bounds__(256) void e_pre_kernel(
        const int* __restrict__ rowptr, const int* __restrict__ csr_src,
        const float* __restrict__ a_s, const float* __restrict__ a_d,
        float* __restrict__ epre, float* __restrict__ mrow, int N) {
    int i = blockIdx.x * blockDim.x + threadIdx.x;
    if (i >= N) return;
    const int b = rowptr[i], e = rowptr[i + 1];
    const float adi = a_d[i];
    float m = -1e30f;
    int j = b;
    for (; j + 2 <= e; j += 2) {
        int s0 = csr_src[j], s1 = csr_src[j + 1];
        float v0 = a_s[s0], v1 = a_s[s1];
        float e0 = v0 + adi, e1 = v1 + adi;
        e0 = e0 > 0.f ? e0 : NEG_SLOPE * e0;
        e1 = e1 > 0.f ? e1 : NEG_SLOPE * e1;
        epre[j] = e0; epre[j + 1] = e1;
        m = fmaxf(m, fmaxf(e0, e1));
    }
    if (j < e) {
        float ev = a_s[csr_src[j]] + adi;
        ev = ev > 0.f ? ev : NEG_SLOPE * ev;
        epre[j] = ev;
        m = fmaxf(m, ev);
    }
    mrow[i] = m;
}

// ---------------------------------------------------------------------------
// GAT aggregate: single-exp weighted gather-sum (max precomputed). 2 nodes
// per wave, 4-deep gather unroll, next-pair rowptr prefetch.
// ---------------------------------------------------------------------------
__global__ void gat_agg_kernel(const int* __restrict__ rowptr, const int* __restrict__ csr_src,
                               const _Float16* __restrict__ g_h, const float* __restrict__ epre,
                               const float* __restrict__ mrow, const float* __restrict__ b2,
                               float* __restrict__ out, int N) {
    const int lane = threadIdx.x & 63;
    const int half = lane >> 5, l32 = lane & 31;
    const int u = l32 & 7, grp = l32 >> 3;         // 4 groups x 8 lanes per node
    const int wib = threadIdx.x >> 6;
    const half4* gh4 = (const half4*)g_h;
    float4* out4 = (float4*)out;
    const float4 b24 = ((const float4*)b2)[u];
    const int npair = (N + 1) >> 1;
    const int pstride = gridDim.x * 4;
    int p = blockIdx.x * 4 + wib;
    int2 be = make_int2(0, 0);
    float mi = 0.f;
    if (p < npair) {
        int i0 = p * 2 + half;
        if (i0 < N) { be = *(const int2*)&rowptr[i0]; mi = mrow[i0]; }
    }
    for (; p < npair; p += pstride) {
        const int i = p * 2 + half;
        const bool act = i < N;
        const int b = be.x, e = be.y;
        const float m_cur = mi;
        int pn = p + pstride;
        if (pn < npair) {
            int i1 = pn * 2 + half;
            if (i1 < N) { be = *(const int2*)&rowptr[i1]; mi = mrow[i1]; }
        }
        float ssum = 0.f;
        float ax = 0.f, ay = 0.f, az = 0.f, aw = 0.f;
        for (int j = b + grp; j < e; j += 16) {    // 4-deep: slots j, j+4, j+8, j+12
            int j1 = j + 4, j2 = j + 8, j3 = j + 12;
            bool v1 = j1 < e, v2 = j2 < e, v3 = j3 < e;
            int s0 = csr_src[j];
            int s1 = csr_src[v1 ? j1 : j];
            int s2 = csr_src[v2 ? j2 : j];
            int s3 = csr_src[v3 ? j3 : j];
            float e0 = epre[j];
            float e1 = epre[v1 ? j1 : j];
            float e2 = epre[v2 ? j2 : j];
            float e3 = epre[v3 ? j3 : j];
            half4 g0 = gh4[s0 * 8 + u];
            half4 g1 = gh4[s1 * 8 + u];
            half4 g2 = gh4[s2 * 8 + u];
            half4 g3 = gh4[s3 * 8 + u];
            float w0 = __expf(e0 - m_cur);
            float w1 = v1 ? __expf(e1 - m_cur) : 0.f;
            float w2 = v2 ? __expf(e2 - m_cur) : 0.f;
            float w3 = v3 ? __expf(e3 - m_cur) : 0.f;
            ssum += w0 + w1 + w2 + w3;
            ax = fmaf(w0, (float)g0.x, fmaf(w1, (float)g1.x, fmaf(w2, (float)g2.x, fmaf(w3, (float)g3.x, ax))));
            ay = fmaf(w0, (float)g0.y, fmaf(w1, (float)g1.y, fmaf(w2, (float)g2.y, fmaf(w3, (float)g3.y, ay))));
            az = fmaf(w0, (float)g0.z, fmaf(w1, (float)g1.z, fmaf(w2, (float)g2.z, fmaf(w3, (float)g3.z, az))));
            aw = fmaf(w0, (float)g0.w, fmaf(w1, (float)g1.w, fmaf(w2, (float)g2.w, fmaf(w3, (float)g3.w, aw))));
        }
        #pragma unroll
        for (int d = 8; d <= 16; d <<= 1) {        // reduce over 4 groups
            ssum += __shfl_xor(ssum, d);
            ax += __shfl_xor(ax, d); ay += __shfl_xor(ay, d);
            az += __shfl_xor(az, d); aw += __shfl_xor(aw, d);
        }
        if (act && grp == 0) {
            float inv = 1.f / (ssum + EPS_F);
            float4 o;
            o.x = fmaf(ax, inv, b24.x); o.y = fmaf(ay, inv, b24.y);
            o.z = fmaf(az, inv, b24.z); o.w = fmaf(aw, inv, b24.w);
            out4[(long long)i * 8 + u] = o;
        }
    }
}

extern "C" void kernel_launch(void* const* d_in, const int* in_sizes, int n_in,
                              void* d_out, int out_size, void* d_ws, size_t ws_size,
                              hipStream_t stream) {
    const float* x       = (const float*)d_in[0];
    const int*   ei      = (const int*)d_in[1];   // int32 or int64, detected on device
    const float* W1      = (const float*)d_in[2];
    const float* b1      = (const float*)d_in[3];
    const float* W2      = (const float*)d_in[4];
    const float* att_src = (const float*)d_in[5];
    const float* att_dst = (const float*)d_in[6];
    const float* b2      = (const float*)d_in[7];
    float* out = (float*)d_out;

    const long long N  = in_sizes[0] / D_IN;
    const long long E  = in_sizes[1] / 2;
    const long long E2 = E + N;
    const int K2  = (int)((N + NPB - 1) >> BKT_SHIFT);              // 196 for N=100K
    const int EPB = (int)((E2 + NBLK_BIN - 1) / NBLK_BIN);
    const int LH  = K2 * NBLK_BIN;
    const int NBH = (LH + 1023) / 1024;

    // workspace layout (256B aligned slices)
    char* ws = (char*)d_ws;
    size_t off0 = 0;
    auto alloc = [&](size_t bytes) -> void* {
        off0 = (off0 + 255) & ~(size_t)255;
        void* p = ws + off0;
        off0 += bytes;
        return p;
    };
    int*   hist     = (int*)  alloc((size_t)KBUKMAX * NBLK_BIN * 4);
    unsigned* bins  = (unsigned*)alloc((size_t)E2 * 4);
    int*   rowptr   = (int*)  alloc((size_t)(N + 1) * 4);
    int*   csr_src  = (int*)  alloc((size_t)E2 * 4);
    float* dis      = (float*)alloc((size_t)N * 4);
    _Float16* hws_h = (_Float16*)alloc((size_t)(N + 1) * D_HID * 2);  // +1 sentinel row
    _Float16* g_h   = (_Float16*)alloc((size_t)(N + 1) * D_OUT * 2);
    float* as       = (float*)alloc((size_t)N * 4);
    float* ad       = (float*)alloc((size_t)N * 4);
    float* epre     = (float*)alloc((size_t)E2 * 4);
    float* mrow     = (float*)alloc((size_t)N * 4);
    int*   bsum     = (int*)  alloc((size_t)NBH * 4);
    (void)ws_size; (void)n_in; (void)out_size;

    hist_kernel<<<NBLK_BIN, 256, 0, stream>>>(ei, E, E2, hist, K2, EPB);
    scan_ga_kernel<<<NBH, 256, 0, stream>>>(hist, bsum, LH);
    scan_flat_kernel<<<1, 1024, 0, stream>>>(bsum, NBH);
    scatter_kernel<<<NBLK_BIN, 256, 0, stream>>>(ei, E, E2, hist, bsum, bins, K2, EPB);
    csr_b_kernel<<<K2, 512, 0, stream>>>(bins, hist, bsum, rowptr, dis, csr_src, (int)N, K2, E2);
    gemm1_kernel<<<(int)((N + 255) / 256), 256, 0, stream>>>(x, W1, dis, hws_h, (int)N);
    gcn_fused_kernel<<<AGG_BLOCKS, 256, 0, stream>>>(rowptr, csr_src, hws_h, dis, b1, W2,
                                                     att_src, att_dst, g_h, as, ad, (int)N);
    e_pre_kernel<<<(int)((N + 255) / 256), 256, 0, stream>>>(rowptr, csr_src, as, ad, epre, mrow, (int)N);
    gat_agg_kernel<<<AGG_BLOCKS, 256, 0, stream>>>(rowptr, csr_src, g_h, epre, mrow, b2, out, (int)N);
}